// Round 6
// baseline (15163.995 us; speedup 1.0000x reference)
//
#include <hip/hip_runtime.h>
#include <hip/hip_bf16.h>

#define T_STEPS 512
#define BATCH   64
#define HID     1024
#define NWG     32          // 4 row-groups x 8 col-slices

typedef __attribute__((ext_vector_type(8))) short short8;
typedef __attribute__((ext_vector_type(4))) float f32x4;

static __device__ __forceinline__ float b2f(unsigned short u){
  union { unsigned u; float f; } c; c.u = ((unsigned)u) << 16; return c.f;
}
static __device__ __forceinline__ unsigned short f2b(float f){
  union { float f; unsigned u; } c; c.f = f;
  unsigned r = c.u + 0x7fffu + ((c.u >> 16) & 1u);
  return (unsigned short)(r >> 16);
}
static __device__ __forceinline__ float sigm(float x){ return 1.0f / (1.0f + __expf(-x)); }
static __device__ __forceinline__ float tanh_fast(float x){ return 2.0f / (1.0f + __expf(-2.0f * x)) - 1.0f; }

// coherent (cache-bypass) 16B load from the fabric coherence point
static __device__ __forceinline__ short8 ldsc(const unsigned short* p){
  unsigned long long a = __hip_atomic_load((const unsigned long long*)p,
                                           __ATOMIC_RELAXED, __HIP_MEMORY_SCOPE_AGENT);
  unsigned long long b = __hip_atomic_load((const unsigned long long*)(p + 4),
                                           __ATOMIC_RELAXED, __HIP_MEMORY_SCOPE_AGENT);
  union { unsigned long long q[2]; short8 s; } u;
  u.q[0] = a; u.q[1] = b; return u.s;
}

#define MFMA __builtin_amdgcn_mfma_f32_16x16x32_bf16

// ---------------- init: zero barrier flags ----------------
__global__ void gru_init_k(int* __restrict__ flags){
  int i = blockIdx.x * blockDim.x + threadIdx.x;
  if (i < NWG)
    __hip_atomic_store(flags + i, 0, __ATOMIC_RELAXED, __HIP_MEMORY_SCOPE_AGENT);
}

// ---------------- transpose + cast weights: Wt[g][n][k] = W_g[k][n] ----------------
__global__ void gru_prepw_k(const float* __restrict__ w0, const float* __restrict__ w1,
                            const float* __restrict__ w2, const float* __restrict__ w3,
                            const float* __restrict__ w4, const float* __restrict__ w5,
                            unsigned short* __restrict__ wt){
  __shared__ float tile[32][33];
  const float* src;
  switch (blockIdx.z){
    case 0: src = w0; break; case 1: src = w1; break; case 2: src = w2; break;
    case 3: src = w3; break; case 4: src = w4; break; default: src = w5; break;
  }
  int tx = threadIdx.x, ty = threadIdx.y;
  int x0 = blockIdx.x * 32, y0 = blockIdx.y * 32;
  #pragma unroll
  for (int i = 0; i < 32; i += 8)
    tile[ty + i][tx] = src[(size_t)(y0 + ty + i) * HID + x0 + tx];
  __syncthreads();
  unsigned short* dst = wt + (size_t)blockIdx.z * HID * HID;
  #pragma unroll
  for (int i = 0; i < 32; i += 8)
    dst[(size_t)(x0 + ty + i) * HID + y0 + tx] = f2b(tile[tx][ty + i]);
}

// ---------------- pre-pass: G2[t][gate][col][row] = (X @ Wx + b), bf16 ----------
// blockIdx.x = t (64 rows), blockIdx.y*256 = col window; 4 waves x 64 cols.
__global__ __launch_bounds__(256, 2) void gru_xproj_k(
    const float* __restrict__ inp,         // [32768][1024] fp32
    const unsigned short* __restrict__ wt, // x-weights slots 0,2,4
    const float* __restrict__ bz, const float* __restrict__ br, const float* __restrict__ bh,
    unsigned short* __restrict__ G2)       // [512][3][1024][64] bf16
{
  const int wv = threadIdx.x >> 6, lane = threadIdx.x & 63;
  const int l16 = lane & 15, kq = lane >> 4;
  const int m0 = blockIdx.x * 64;
  const int n0 = blockIdx.y * 256 + wv * 64;

  const unsigned short* wb[4];
  float bias[4];
  #pragma unroll
  for (int c = 0; c < 4; ++c){
    int n = n0 + c * 16 + l16;
    int g = n >> 10, cc = n & 1023;
    wb[c] = wt + (size_t)(2 * g) * HID * HID + (size_t)cc * HID + kq * 8;
    bias[c] = (g == 0 ? bz : (g == 1 ? br : bh))[cc];
  }
  const float* arow[4];
  #pragma unroll
  for (int r = 0; r < 4; ++r)
    arow[r] = inp + (size_t)(m0 + r * 16 + l16) * HID + kq * 8;

  f32x4 acc[4][4];
  #pragma unroll
  for (int r = 0; r < 4; ++r)
    #pragma unroll
    for (int c = 0; c < 4; ++c) acc[r][c] = (f32x4){0.f,0.f,0.f,0.f};

  #pragma unroll 2
  for (int kk = 0; kk < HID; kk += 32){
    short8 af[4], bf[4];
    #pragma unroll
    for (int r = 0; r < 4; ++r){
      float4 f0 = *(const float4*)(arow[r] + kk);
      float4 f1 = *(const float4*)(arow[r] + kk + 4);
      short8 a;
      a[0]=(short)f2b(f0.x); a[1]=(short)f2b(f0.y); a[2]=(short)f2b(f0.z); a[3]=(short)f2b(f0.w);
      a[4]=(short)f2b(f1.x); a[5]=(short)f2b(f1.y); a[6]=(short)f2b(f1.z); a[7]=(short)f2b(f1.w);
      af[r] = a;
    }
    #pragma unroll
    for (int c = 0; c < 4; ++c) bf[c] = *(const short8*)(wb[c] + kk);
    #pragma unroll
    for (int r = 0; r < 4; ++r)
      #pragma unroll
      for (int c = 0; c < 4; ++c)
        acc[r][c] = MFMA(af[r], bf[c], acc[r][c], 0, 0, 0);
  }

  #pragma unroll
  for (int c = 0; c < 4; ++c){
    int n = n0 + c * 16 + l16;
    int g = n >> 10, cc = n & 1023;
    #pragma unroll
    for (int r = 0; r < 4; ++r){
      unsigned lo = (unsigned)f2b(acc[r][c][0] + bias[c]) | ((unsigned)f2b(acc[r][c][1] + bias[c]) << 16);
      unsigned hi = (unsigned)f2b(acc[r][c][2] + bias[c]) | ((unsigned)f2b(acc[r][c][3] + bias[c]) << 16);
      *(unsigned long long*)&G2[((size_t)(blockIdx.x * 3 + g) * 1024 + cc) * 64 + r * 16 + kq * 4] =
        (unsigned long long)lo | ((unsigned long long)hi << 32);
    }
  }
}

// ---------------- wave-0-only flag poll over this row-group's 8 flags ----------------
static __device__ __forceinline__ void waitflags(const int* fgrp){
  int lane = threadIdx.x & 63;
  // target passed via template-free arg below
}
static __device__ __forceinline__ void waitflags8(const int* fgrp, int target){
  int idx = (threadIdx.x & 63) & 7;
  for (;;){
    int v = __hip_atomic_load(fgrp + idx, __ATOMIC_RELAXED, __HIP_MEMORY_SCOPE_AGENT);
    if (__all(v >= target)) return;
  }
}

// stage a 16x1024 bf16 tile (32KB) from coherent global into swizzled LDS
static __device__ __forceinline__ void stage_in(const unsigned short* __restrict__ src,
                                                unsigned short* __restrict__ stg, int tid){
  const int lin = tid * 32;                 // shorts
  const int sw  = ((tid >> 5) & 7) << 4;    // byte XOR (row&7)<<4
  short8 v0 = ldsc(src + lin);
  short8 v1 = ldsc(src + lin + 8);
  short8 v2 = ldsc(src + lin + 16);
  short8 v3 = ldsc(src + lin + 24);
  char* sb = (char*)stg;
  const int b = lin * 2;
  *(short8*)(sb + ((b     ) ^ sw)) = v0;
  *(short8*)(sb + ((b + 16) ^ sw)) = v1;
  *(short8*)(sb + ((b + 32) ^ sw)) = v2;
  *(short8*)(sb + ((b + 48) ^ sw)) = v3;
}

// ---------------- persistent GRU scan: 4 row-groups x 8 col-slices ----------------
__global__ __launch_bounds__(512, 1) void gru_scan_k(
    const unsigned short* __restrict__ G2,    // [512][3][1024][64] bf16
    const unsigned short* __restrict__ wt,    // [6][1024][1024] bf16 [n][k]
    float* __restrict__ out,                  // [T][64][1024] fp32 + [64][1024] H_final
    unsigned short* __restrict__ hb,          // [4][16][1024] bf16 H   (coherence point)
    unsigned short* __restrict__ rh,          // [4][16][1024] bf16 R*H (coherence point)
    int* __restrict__ flags)                  // [32]
{
  __shared__ __align__(16) unsigned short stage[16 * 1024];  // 32 KiB staged H or R*H
  __shared__ __align__(16) unsigned short ostage[16 * 128];  // 4 KiB publish slice
  __shared__ float hlds[16 * 128];                           // own-slice H fp32
  __shared__ float zlds[16 * 128];                           // own-slice Z fp32

  const int bid = blockIdx.x;
  const int rg  = bid & 3;          // row-group: batch rows [rg*16, +16)
  const int cs  = bid >> 2;         // col-slice: hid cols  [cs*128, +128)
  const int tid  = threadIdx.x;
  const int wave = tid >> 6;
  const int lane = tid & 63;
  const int l16  = lane & 15;
  const int kq   = lane >> 4;
  const bool zp  = wave < 4;        // phase A: waves 0-3 Z, 4-7 R
  const int w3   = wave & 3;
  const int rowj0 = kq * 4;         // C-frag row base within the 16-row group

  int* fgrp = flags + rg * 8;
  int* myflag = fgrp + cs;

  // phase A: each wave covers 2 col-tiles (32 cols); phase B: 1 col-tile (16 cols)
  const int nA0 = cs * 128 + w3 * 32 + l16;
  const int nB  = cs * 128 + wave * 16 + l16;

  const unsigned short* wbA0 = wt + (size_t)(zp ? 1 : 3) * HID * HID + (size_t)nA0 * HID + kq * 8;
  const unsigned short* wbA1 = wbA0 + (size_t)16 * HID;
  const unsigned short* wbB  = wt + (size_t)5 * HID * HID + (size_t)nB * HID + kq * 8;

  const unsigned short* hsrc = hb + rg * 16384;
  const unsigned short* rsrc = rh + rg * 16384;

  const int abase = l16 * 2048 + kq * 16;     // byte base of A-frag in stage
  const int asw   = (l16 & 7) << 4;

  const int ps   = tid * 4;                   // publish: shorts in ostage
  const int prow = ps >> 7, pcol = ps & 127;
  unsigned short* hdst = hb + rg * 16384 + prow * 1024 + cs * 128 + pcol;
  unsigned short* rdst = rh + rg * 16384 + prow * 1024 + cs * 128 + pcol;

  float h[4] = {0.f, 0.f, 0.f, 0.f};

  for (int t = 0; t < T_STEPS; ++t){
    // ---- early (pre-wait) cached loads of this step's x-gate values ----
    const size_t gstep = (size_t)t * 3 * 1024 * 64;
    unsigned long long u0 = *(const unsigned long long*)
        (G2 + gstep + ((size_t)(zp ? 0 : 1) * 1024 + nA0) * 64 + rg * 16 + rowj0);
    unsigned long long u1 = *(const unsigned long long*)
        (G2 + gstep + ((size_t)(zp ? 0 : 1) * 1024 + nA0 + 16) * 64 + rg * 16 + rowj0);
    unsigned long long u2 = *(const unsigned long long*)
        (G2 + gstep + ((size_t)2 * 1024 + nB) * 64 + rg * 16 + rowj0);

    // ---- phase A: Z (waves 0-3) / R (waves 4-7) over this slice ----
    f32x4 a00 = {0,0,0,0}, a01 = {0,0,0,0}, a10 = {0,0,0,0}, a11 = {0,0,0,0};
    if (t){
      if (wave == 0) waitflags8(fgrp, 2 * t);      // H_{t-1} published by row-group
      __syncthreads();
      stage_in(hsrc, stage, tid);
      __syncthreads();
      const char* sb = (const char*)stage;
      #pragma unroll 4
      for (int c = 0; c < 32; c += 2){
        short8 af0 = *(const short8*)(sb + ((abase + c * 64) ^ asw));
        short8 af1 = *(const short8*)(sb + ((abase + c * 64 + 64) ^ asw));
        a00 = MFMA(af0, *(const short8*)(wbA0 + c * 32),      a00, 0, 0, 0);
        a01 = MFMA(af1, *(const short8*)(wbA0 + c * 32 + 32), a01, 0, 0, 0);
        a10 = MFMA(af0, *(const short8*)(wbA1 + c * 32),      a10, 0, 0, 0);
        a11 = MFMA(af1, *(const short8*)(wbA1 + c * 32 + 32), a11, 0, 0, 0);
      }
    }
    #pragma unroll
    for (int j = 0; j < 4; ++j){
      float g0 = sigm(a00[j] + a01[j] + b2f((unsigned short)(u0 >> (16 * j))));
      float g1 = sigm(a10[j] + a11[j] + b2f((unsigned short)(u1 >> (16 * j))));
      int i0 = (rowj0 + j) * 128 + w3 * 32 + l16;
      if (zp){
        zlds[i0] = g0; zlds[i0 + 16] = g1;
      } else {
        float hp0 = t ? hlds[i0] : 0.f;
        float hp1 = t ? hlds[i0 + 16] : 0.f;
        ostage[i0] = f2b(g0 * hp0); ostage[i0 + 16] = f2b(g1 * hp1);
      }
    }
    __syncthreads();                                  // zlds / ostage complete
    if (t){
      __hip_atomic_store((unsigned long long*)rdst, *(const unsigned long long*)&ostage[ps],
                         __ATOMIC_RELAXED, __HIP_MEMORY_SCOPE_AGENT);
      __syncthreads();                                // every wave drains its stores
      if (tid == 0){
        asm volatile("s_waitcnt vmcnt(0)" ::: "memory");
        __hip_atomic_store(myflag, 2 * t + 1, __ATOMIC_RELAXED, __HIP_MEMORY_SCOPE_AGENT);
      }
    }

    // ---- phase B: H_tilde + combine, all 8 waves (16 cols each) ----
    f32x4 c0 = {0,0,0,0}, c1 = {0,0,0,0};
    if (t){
      if (wave == 0) waitflags8(fgrp, 2 * t + 1);     // R*H published by row-group
      __syncthreads();
      stage_in(rsrc, stage, tid);
      __syncthreads();
      const char* sb = (const char*)stage;
      #pragma unroll 4
      for (int c = 0; c < 32; c += 2){
        short8 af0 = *(const short8*)(sb + ((abase + c * 64) ^ asw));
        short8 af1 = *(const short8*)(sb + ((abase + c * 64 + 64) ^ asw));
        c0 = MFMA(af0, *(const short8*)(wbB + c * 32),      c0, 0, 0, 0);
        c1 = MFMA(af1, *(const short8*)(wbB + c * 32 + 32), c1, 0, 0, 0);
      }
    }
    #pragma unroll
    for (int j = 0; j < 4; ++j){
      int ib = (rowj0 + j) * 128 + wave * 16 + l16;
      float ht = tanh_fast(c0[j] + c1[j] + b2f((unsigned short)(u2 >> (16 * j))));
      float z  = zlds[ib];
      float hn = z * h[j] + (1.0f - z) * ht;
      h[j] = hn;
      hlds[ib] = hn;
      ostage[ib] = f2b(hn);
    }
    __syncthreads();                                  // ostage / hlds complete
    if (t < T_STEPS - 1){
      __hip_atomic_store((unsigned long long*)hdst, *(const unsigned long long*)&ostage[ps],
                         __ATOMIC_RELAXED, __HIP_MEMORY_SCOPE_AGENT);
      __syncthreads();
      if (tid == 0){
        asm volatile("s_waitcnt vmcnt(0)" ::: "memory");
        __hip_atomic_store(myflag, 2 * t + 2, __ATOMIC_RELAXED, __HIP_MEMORY_SCOPE_AGENT);
      }
    }
    // out stores: off the critical path, never read by other WGs
    #pragma unroll
    for (int j = 0; j < 4; ++j){
      __builtin_nontemporal_store(h[j], &out[((size_t)t * BATCH + rg * 16 + rowj0 + j) * HID + nB]);
      if (t == T_STEPS - 1)
        __builtin_nontemporal_store(h[j],
            &out[(size_t)T_STEPS * BATCH * HID + (size_t)(rg * 16 + rowj0 + j) * HID + nB]);
    }
  }
}

extern "C" void kernel_launch(void* const* d_in, const int* in_sizes, int n_in,
                              void* d_out, int out_size, void* d_ws, size_t ws_size,
                              hipStream_t stream){
  const float* inputs = (const float*)d_in[0];
  const float* W_xz = (const float*)d_in[1];
  const float* W_hz = (const float*)d_in[2];
  const float* b_z  = (const float*)d_in[3];
  const float* W_xr = (const float*)d_in[4];
  const float* W_hr = (const float*)d_in[5];
  const float* b_r  = (const float*)d_in[6];
  const float* W_xh = (const float*)d_in[7];
  const float* W_hh = (const float*)d_in[8];
  const float* b_h  = (const float*)d_in[9];
  float* out = (float*)d_out;

  char* ws = (char*)d_ws;
  int*            flags = (int*)ws;                                  // 128 B (pad 4 KiB)
  unsigned short* hb    = (unsigned short*)(ws + 4096);              // 128 KiB [4][16][1024]
  unsigned short* rh    = (unsigned short*)(ws + 4096 + 131072);     // 128 KiB
  unsigned short* wt    = (unsigned short*)(ws + 266240);            // 12 MiB
  unsigned short* G2    = (unsigned short*)(ws + 266240 + 12582912); // 192 MiB
  // total ws needed: ~204 MB (same as round 5)

  gru_init_k<<<1, 64, 0, stream>>>(flags);
  gru_prepw_k<<<dim3(32, 32, 6), dim3(32, 8), 0, stream>>>(W_xz, W_hz, W_xr, W_hr, W_xh, W_hh, wt);
  gru_xproj_k<<<dim3(512, 12), 256, 0, stream>>>(inputs, wt, b_z, b_r, b_h, G2);
  gru_scan_k<<<NWG, 512, 0, stream>>>(G2, wt, out, hb, rh, flags);
}